// Round 9
// baseline (131.964 us; speedup 1.0000x reference)
//
#include <hip/hip_runtime.h>
#include <stdint.h>

// Problem dims (fixed by reference)
#define NR    4096
#define D_DIM 512
#define MC    4096
#define KC    2048

typedef unsigned short u16;
typedef __attribute__((ext_vector_type(8))) short bf16x8;
typedef __attribute__((ext_vector_type(4))) float f32x4;

__device__ __forceinline__ u16 f2bf(float f) {
  union { float f; uint32_t u; } v; v.f = f;
  return (u16)((v.u + 0x7FFFu + ((v.u >> 16) & 1u)) >> 16);  // RNE
}
__device__ __forceinline__ float bf2f(u16 h) {
  union { uint32_t u; float f; } v; v.u = (uint32_t)h << 16; return v.f;
}
__device__ __forceinline__ void gload16(const void* g, void* lds) {
  __builtin_amdgcn_global_load_lds((const __attribute__((address_space(1))) void*)g,
                                   (__attribute__((address_space(3))) void*)lds,
                                   16, 0, 0);
}

// ---- 128x128xBK64 bf16 MFMA tile; double-buffered LDS + XOR slot-swizzle ----
// (structure proven R8: swizzle via pre-swizzled GLOBAL src + XOR'd LDS read;
//  STAGE issued before compute; one __syncthreads per step)
// STEPS = compile-time K-step count (kEnd-kBeg)/64; buffers statically selected.
// EPI 0: Cf[idx] = v               (split-K partials; caller bakes z-offset into Cf)
// EPI 2: Cf[idx] = sqrt(max(tv[col] - 2v + sv[row], 0))
// EPI 3: Cbf[idx] = bf16(v); vatom[row] += sum_col v*bf16(DotH[idx])
// EPI 4: no store;           vatom[row] += sum_col v*DotF[idx]
template <int EPI, int STEPS>
__device__ __forceinline__ void gemm_tile(
    const u16* __restrict__ Ag, const u16* __restrict__ Bg,
    float* __restrict__ Cf, u16* __restrict__ Cbf,
    const u16* __restrict__ DotH, const float* __restrict__ DotF,
    float* __restrict__ vatom, const float* __restrict__ tv, const float* __restrict__ sv,
    int m0, int n0, int Ndim, int Kdim, int kBeg,
    u16* As0, u16* As1, u16* Bs0, u16* Bs1, int tid)
{
  const int rowt = tid >> 3;                                // 0..31 (+c*32)
  const int cswz = ((tid & 7) ^ ((tid >> 3) & 7)) << 3;     // swizzled k-slot (u16)
  const int wave = tid >> 6, lane = tid & 63;
  const int wr = (wave >> 1) << 6, wc = (wave & 1) << 6;
  const int fr = lane & 15;
  const int sw = fr & 7;                                    // read XOR = row&7
  const int hq = lane >> 4;                                 // 16B-slot base 0..3
  const int wb = wave << 10;                                // wave LDS byte base

  f32x4 acc[4][4] = {};
  const u16* agB = Ag + (size_t)(m0 + rowt) * Kdim + cswz;
  const u16* bgB = Bg + (size_t)(n0 + rowt) * Kdim + cswz;

  #define STAGE(k0, Asb, Bsb)                                          \
    _Pragma("unroll")                                                  \
    for (int c = 0; c < 4; ++c) {                                      \
      gload16(agB + (k0) + (size_t)(c * 32) * Kdim, (char*)(Asb) + c * 4096 + wb); \
      gload16(bgB + (k0) + (size_t)(c * 32) * Kdim, (char*)(Bsb) + c * 4096 + wb); \
    }

  STAGE(kBeg, As0, Bs0)
  __syncthreads();

  #pragma unroll
  for (int t = 0; t < STEPS; ++t) {
    u16* Ac = (t & 1) ? As1 : As0;          // t compile-time -> static selection
    u16* Bc = (t & 1) ? Bs1 : Bs0;
    if (t + 1 < STEPS) {
      u16* An = (t & 1) ? As0 : As1;
      u16* Bn = (t & 1) ? Bs0 : Bs1;
      STAGE(kBeg + (t + 1) * 64, An, Bn)    // prefetch BEFORE compute
    }
    #pragma unroll
    for (int kk = 0; kk < 64; kk += 32) {
      const int so = ((((kk >> 3) + hq) ^ sw) << 3);   // swizzled LDS u16 offset
      bf16x8 a[4], b[4];
      #pragma unroll
      for (int i = 0; i < 4; ++i) a[i] = *(const bf16x8*)&Ac[(wr + i * 16 + fr) * 64 + so];
      #pragma unroll
      for (int j = 0; j < 4; ++j) b[j] = *(const bf16x8*)&Bc[(wc + j * 16 + fr) * 64 + so];
      #pragma unroll
      for (int i = 0; i < 4; ++i)
        #pragma unroll
        for (int j = 0; j < 4; ++j)
          acc[i][j] = __builtin_amdgcn_mfma_f32_16x16x32_bf16(a[i], b[j], acc[i][j], 0, 0, 0);
    }
    __syncthreads();   // drains prefetch (vmcnt) + ds_reads (lgkmcnt), one per step
  }
  #undef STAGE

  // C/D mapping (verified): col = lane&15, row = (lane>>4)*4 + reg
  const int q = lane >> 4;
  #pragma unroll
  for (int i = 0; i < 4; ++i) {
    #pragma unroll
    for (int r = 0; r < 4; ++r) {
      const int grow = m0 + wr + i * 16 + q * 4 + r;
      float p = 0.f;
      #pragma unroll
      for (int j = 0; j < 4; ++j) {
        const int gcol = n0 + wc + j * 16 + fr;
        const float v = acc[i][j][r];
        const size_t idx = (size_t)grow * Ndim + gcol;
        if (EPI == 0) Cf[idx] = v;
        if (EPI == 2) { float sq = tv[gcol] - 2.f * v + sv[grow]; Cf[idx] = sqrtf(fmaxf(sq, 0.f)); }
        if (EPI == 3) { Cbf[idx] = f2bf(v); p += v * bf2f(DotH[idx]); }
        if (EPI == 4) { p += v * DotF[idx]; }
      }
      if (EPI == 3 || EPI == 4) {
        #pragma unroll
        for (int off = 1; off < 16; off <<= 1) p += __shfl_xor(p, off);
        if (fr == 0) atomicAdd(&vatom[grow], p);
      }
    }
  }
}

// transpose+cvt one 32x32 tile: out[c][r] = bf16(in[r][c])
__device__ __forceinline__ void transpose_tile(
    const float* __restrict__ in, u16* __restrict__ out, int R, int C,
    int rt, int ct, int tid, float* tile /* 32*33 floats */)
{
  const int tx = tid & 31, ty = tid >> 5;  // 32 x 8
  #pragma unroll
  for (int i = 0; i < 32; i += 8)
    tile[(size_t)(ty + i) * 33 + tx] = in[(size_t)(rt + ty + i) * C + ct + tx];
  __syncthreads();
  #pragma unroll
  for (int i = 0; i < 32; i += 8)
    out[(size_t)(ct + ty + i) * R + rt + tx] = f2bf(tile[(size_t)tx * 33 + ty + i]);
  __syncthreads();
}

// ---- kernel 1: X-transpose only (critical path for g_gemm) + zero t/s vecs ----
__global__ __launch_bounds__(256)
void xprep(const float* __restrict__ X, u16* __restrict__ XT_bf,
           float* __restrict__ tvec)
{
  __shared__ float tile[32 * 33];
  const int b = blockIdx.x, tid = threadIdx.x;
  int zi = b * 256 + tid;
  if (zi < 4096 + 2048) tvec[zi] = 0.f;
  // X [4096][512] -> XT_bf [512][4096]; 2048 tiles = 128 r-tiles x 16 c-tiles
  #pragma unroll 1
  for (int j = 0; j < 4; ++j) {
    int T = b * 4 + j;
    transpose_tile(X, XT_bf, NR, D_DIM, (T >> 4) * 32, (T & 15) * 32, tid, tile);
  }
}

// ---- kernel 2: blocks 0-255: G = X^T X split-K z=16 partials (dispatched first);
//      blocks 256-767: M-transpose; 768-895: C cvt ----
__global__ __launch_bounds__(256)
void gmc(const u16* __restrict__ XT_bf, float* __restrict__ Gpart,
         const float* __restrict__ Mm, const float* __restrict__ Cc,
         u16* __restrict__ M_bfT, u16* __restrict__ C_bf)
{
  __shared__ __align__(16) u16 As[2][8192];
  __shared__ __align__(16) u16 Bs[2][8192];
  const int b = blockIdx.x, tid = threadIdx.x;
  if (b < 256) {
    const int t = b & 15, z = b >> 4;
    const int n0 = (t & 3) * 128, m0 = (t >> 2) * 128;
    gemm_tile<0, 4>(XT_bf, XT_bf, Gpart + (size_t)z * 512 * 512, nullptr, nullptr,
                    nullptr, nullptr, nullptr, nullptr, m0, n0, 512, NR, z * 256,
                    As[0], As[1], Bs[0], Bs[1], tid);
  } else if (b < 768) {
    float* ttile = (float*)As;
    #pragma unroll 1
    for (int j = 0; j < 4; ++j) {
      int T = (b - 256) * 4 + j;   // 2048 tiles = 16 r-tiles x 128 c-tiles
      transpose_tile(Mm, M_bfT, D_DIM, MC, (T >> 7) * 32, (T & 127) * 32, tid, ttile);
    }
  } else {
    const int bb = b - 768;
    const float4* C4 = (const float4*)Cc;
    #pragma unroll 1
    for (int i = bb * 256 + tid; i < (KC * D_DIM) / 4; i += 128 * 256) {
      float4 v = C4[i];
      ushort4 r; r.x = f2bf(v.x); r.y = f2bf(v.y); r.z = f2bf(v.z); r.w = f2bf(v.w);
      *(ushort4*)&C_bf[(size_t)i * 4] = r;
    }
  }
}

// ---- kernel 3: reduce 16 partials -> G_bf. grid 256 (deterministic z-order) ----
__global__ __launch_bounds__(256)
void reduce_g(const float* __restrict__ Gpart, u16* __restrict__ G_bf)
{
  const float4* P4 = (const float4*)Gpart;
  int i = blockIdx.x * 256 + threadIdx.x;   // 65536 float4 over 65536 threads
  float4 s = {0.f, 0.f, 0.f, 0.f};
  #pragma unroll
  for (int z = 0; z < 16; ++z) {
    float4 v = P4[(size_t)z * (512 * 512 / 4) + i];
    s.x += v.x; s.y += v.y; s.z += v.z; s.w += v.w;
  }
  ushort4 r; r.x = f2bf(s.x); r.y = f2bf(s.y); r.z = f2bf(s.z); r.w = f2bf(s.w);
  *(ushort4*)&G_bf[(size_t)i * 4] = r;
}

// ---- kernel 4: mid. blocks 0-127: A^T = M^T G (+fused t); 128-191: s (+H elided) ----
__global__ __launch_bounds__(256)
void mid(const u16* __restrict__ M_bfT, const u16* __restrict__ C_bf,
         const u16* __restrict__ G_bf, const float* __restrict__ Cc,
         u16* __restrict__ A_bfT, float* __restrict__ tvec)
{
  __shared__ __align__(16) u16 As[2][8192];
  __shared__ __align__(16) u16 Bs[2][8192];
  const int b = blockIdx.x, tid = threadIdx.x;
  if (b < 128) {
    const int n0 = (b & 3) * 128, m0 = (b >> 2) * 128;
    gemm_tile<3, 8>(M_bfT, G_bf, nullptr, A_bfT, M_bfT, nullptr, tvec, nullptr, nullptr,
                    m0, n0, 512, 512, 0, As[0], As[1], Bs[0], Bs[1], tid);
  } else {
    const int u = b - 128;
    const int n0 = (u & 3) * 128, m0 = (u >> 2) * 128;
    gemm_tile<4, 8>(C_bf, G_bf, nullptr, nullptr, nullptr, Cc, tvec + 4096, nullptr,
                    nullptr, m0, n0, 512, 512, 0, As[0], As[1], Bs[0], Bs[1], tid);
  }
}

// ---- kernel 5: final. grid (32,16): out = sqrt(max(t[m] - 2*(C A^T) + s[k], 0)) ----
__global__ __launch_bounds__(256)
void final_gemm(const u16* __restrict__ C_bf, const u16* __restrict__ A_bfT,
                const float* __restrict__ tvec, float* __restrict__ out)
{
  __shared__ __align__(16) u16 As[2][8192];
  __shared__ __align__(16) u16 Bs[2][8192];
  const int n0 = blockIdx.x * 128, m0 = blockIdx.y * 128;
  gemm_tile<2, 8>(C_bf, A_bfT, out, nullptr, nullptr, nullptr, nullptr, tvec,
                  tvec + 4096, m0, n0, MC, 512, 0,
                  As[0], As[1], Bs[0], Bs[1], threadIdx.x);
}

extern "C" void kernel_launch(void* const* d_in, const int* in_sizes, int n_in,
                              void* d_out, int out_size, void* d_ws, size_t ws_size,
                              hipStream_t stream) {
  const float* X  = (const float*)d_in[0];  // [4096][512]
  const float* Mm = (const float*)d_in[1];  // [512][4096]
  const float* Cc = (const float*)d_in[2];  // [2048][512]
  float* out = (float*)d_out;               // [2048][4096]

  char* ws = (char*)d_ws;
  const size_t MB = 1u << 20;
  u16*   XT_bf = (u16*)(ws);                 // [512][4096] bf16, 4MB
  u16*   C_bf  = (u16*)(ws + 4 * MB);        // [2048][512] bf16, 2MB
  u16*   M_bfT = (u16*)(ws + 6 * MB);        // [4096][512] bf16, 4MB
  u16*   A_bfT = (u16*)(ws + 10 * MB);       // [4096][512] bf16, 4MB
  u16*   G_bf  = (u16*)(ws + 14 * MB);       // [512][512] bf16, 0.5MB
  float* tvec  = (float*)(ws + 14 * MB + 512 * 1024);  // [4096]+[2048] f32 (t then s)
  float* Gpart = (float*)(ws + 15 * MB);     // 16 x [512][512] f32, 16MB

  xprep<<<512, 256, 0, stream>>>(X, XT_bf, tvec);
  gmc<<<896, 256, 0, stream>>>(XT_bf, Gpart, Mm, Cc, M_bfT, C_bf);
  reduce_g<<<256, 256, 0, stream>>>(Gpart, G_bf);
  mid<<<192, 256, 0, stream>>>(M_bfT, C_bf, G_bf, Cc, A_bfT, tvec);
  final_gemm<<<dim3(32, 16), 256, 0, stream>>>(C_bf, A_bfT, tvec, out);
}

// Round 10
// 120.010 us; speedup vs baseline: 1.0996x; 1.0996x over previous
//
#include <hip/hip_runtime.h>
#include <stdint.h>

// Problem dims (fixed by reference)
#define NR    4096
#define D_DIM 512
#define MC    4096
#define KC    2048

typedef unsigned short u16;
typedef __attribute__((ext_vector_type(8))) short bf16x8;
typedef __attribute__((ext_vector_type(4))) float f32x4;

__device__ __forceinline__ u16 f2bf(float f) {
  union { float f; uint32_t u; } v; v.f = f;
  return (u16)((v.u + 0x7FFFu + ((v.u >> 16) & 1u)) >> 16);  // RNE
}
__device__ __forceinline__ float bf2f(u16 h) {
  union { uint32_t u; float f; } v; v.u = (uint32_t)h << 16; return v.f;
}
__device__ __forceinline__ void gload16(const void* g, void* lds) {
  __builtin_amdgcn_global_load_lds((const __attribute__((address_space(1))) void*)g,
                                   (__attribute__((address_space(3))) void*)lds,
                                   16, 0, 0);
}

// ---- 128x128xBK64 bf16 MFMA tile; dbuf LDS + XOR slot-swizzle (R8-proven) ----
// R10 change: T4 counted-vmcnt pipeline (m139/m218 pattern). Per step:
//   STAGE(t+1) ; s_waitcnt vmcnt(8) ; s_barrier   <- t's 8 loads landed, t+1's fly
//   compute(t) ; s_barrier                        <- all waves done reading buf t
// No __syncthreads in the loop -> no vmcnt(0) drain of the prefetch.
// Buffer-reuse safety: STAGE(t+2) (next iter) writes buf[t&1]; issued only after
// the trailing barrier, and each wave's ds_reads of buf[t] completed before its
// MFMAs consumed them (compiler lgkmcnt waits), hence before that barrier.
// EPI 0: Cf[idx] = v               (split-K partials; caller bakes z-offset into Cf)
// EPI 2: Cf[idx] = sqrt(max(tv[col] - 2v + sv[row], 0))
// EPI 3: Cbf[idx] = bf16(v); vatom[row] += sum_col v*bf16(DotH[idx])
// EPI 4: no store;           vatom[row] += sum_col v*DotF[idx]
template <int EPI, int STEPS>
__device__ __forceinline__ void gemm_tile(
    const u16* __restrict__ Ag, const u16* __restrict__ Bg,
    float* __restrict__ Cf, u16* __restrict__ Cbf,
    const u16* __restrict__ DotH, const float* __restrict__ DotF,
    float* __restrict__ vatom, const float* __restrict__ tv, const float* __restrict__ sv,
    int m0, int n0, int Ndim, int Kdim, int kBeg,
    u16* As0, u16* As1, u16* Bs0, u16* Bs1, int tid)
{
  const int rowt = tid >> 3;                                // 0..31 (+c*32)
  const int cswz = ((tid & 7) ^ ((tid >> 3) & 7)) << 3;     // swizzled k-slot (u16)
  const int wave = tid >> 6, lane = tid & 63;
  const int wr = (wave >> 1) << 6, wc = (wave & 1) << 6;
  const int fr = lane & 15;
  const int sw = fr & 7;                                    // read XOR = row&7
  const int hq = lane >> 4;                                 // 16B-slot base 0..3
  const int wb = wave << 10;                                // wave LDS byte base

  f32x4 acc[4][4] = {};
  const u16* agB = Ag + (size_t)(m0 + rowt) * Kdim + cswz;
  const u16* bgB = Bg + (size_t)(n0 + rowt) * Kdim + cswz;

  #define STAGE(k0, Asb, Bsb)                                          \
    _Pragma("unroll")                                                  \
    for (int c = 0; c < 4; ++c) {                                      \
      gload16(agB + (k0) + (size_t)(c * 32) * Kdim, (char*)(Asb) + c * 4096 + wb); \
      gload16(bgB + (k0) + (size_t)(c * 32) * Kdim, (char*)(Bsb) + c * 4096 + wb); \
    }

  STAGE(kBeg, As0, Bs0)   // prologue fill of buf0; synced by iter-0's vmcnt+barrier

  #pragma unroll
  for (int t = 0; t < STEPS; ++t) {
    u16* Ac = (t & 1) ? As1 : As0;          // t compile-time -> static selection
    u16* Bc = (t & 1) ? Bs1 : Bs0;
    if (t + 1 < STEPS) {
      u16* An = (t & 1) ? As0 : As1;
      u16* Bn = (t & 1) ? Bs0 : Bs1;
      STAGE(kBeg + (t + 1) * 64, An, Bn)    // 8 loads for t+1 stay in flight
      asm volatile("s_waitcnt vmcnt(8)\n\ts_barrier" ::: "memory");
    } else {
      asm volatile("s_waitcnt vmcnt(0)\n\ts_barrier" ::: "memory");
    }
    __builtin_amdgcn_sched_barrier(0);      // pin: nothing hoists above the wait
    #pragma unroll
    for (int kk = 0; kk < 64; kk += 32) {
      const int so = ((((kk >> 3) + hq) ^ sw) << 3);   // swizzled LDS u16 offset
      bf16x8 a[4], b[4];
      #pragma unroll
      for (int i = 0; i < 4; ++i) a[i] = *(const bf16x8*)&Ac[(wr + i * 16 + fr) * 64 + so];
      #pragma unroll
      for (int j = 0; j < 4; ++j) b[j] = *(const bf16x8*)&Bc[(wc + j * 16 + fr) * 64 + so];
      #pragma unroll
      for (int i = 0; i < 4; ++i)
        #pragma unroll
        for (int j = 0; j < 4; ++j)
          acc[i][j] = __builtin_amdgcn_mfma_f32_16x16x32_bf16(a[i], b[j], acc[i][j], 0, 0, 0);
    }
    if (t + 1 < STEPS)
      asm volatile("s_barrier" ::: "memory");  // buf[t] free for STAGE(t+2)
  }
  #undef STAGE

  // C/D mapping (verified): col = lane&15, row = (lane>>4)*4 + reg
  const int q = lane >> 4;
  #pragma unroll
  for (int i = 0; i < 4; ++i) {
    #pragma unroll
    for (int r = 0; r < 4; ++r) {
      const int grow = m0 + wr + i * 16 + q * 4 + r;
      float p = 0.f;
      #pragma unroll
      for (int j = 0; j < 4; ++j) {
        const int gcol = n0 + wc + j * 16 + fr;
        const float v = acc[i][j][r];
        const size_t idx = (size_t)grow * Ndim + gcol;
        if (EPI == 0) Cf[idx] = v;
        if (EPI == 2) { float sq = tv[gcol] - 2.f * v + sv[grow]; Cf[idx] = sqrtf(fmaxf(sq, 0.f)); }
        if (EPI == 3) { Cbf[idx] = f2bf(v); p += v * bf2f(DotH[idx]); }
        if (EPI == 4) { p += v * DotF[idx]; }
      }
      if (EPI == 3 || EPI == 4) {
        #pragma unroll
        for (int off = 1; off < 16; off <<= 1) p += __shfl_xor(p, off);
        if (fr == 0) atomicAdd(&vatom[grow], p);
      }
    }
  }
}

// transpose+cvt one 32x32 tile: out[c][r] = bf16(in[r][c])
__device__ __forceinline__ void transpose_tile(
    const float* __restrict__ in, u16* __restrict__ out, int R, int C,
    int rt, int ct, int tid, float* tile /* 32*33 floats */)
{
  const int tx = tid & 31, ty = tid >> 5;  // 32 x 8
  #pragma unroll
  for (int i = 0; i < 32; i += 8)
    tile[(size_t)(ty + i) * 33 + tx] = in[(size_t)(rt + ty + i) * C + ct + tx];
  __syncthreads();
  #pragma unroll
  for (int i = 0; i < 32; i += 8)
    out[(size_t)(ct + ty + i) * R + rt + tx] = f2bf(tile[(size_t)tx * 33 + ty + i]);
  __syncthreads();
}

// ---- kernel 1: X-transpose (critical path for gmc) + zero t/s vecs ----
__global__ __launch_bounds__(256)
void xprep(const float* __restrict__ X, u16* __restrict__ XT_bf,
           float* __restrict__ tvec)
{
  __shared__ float tile[32 * 33];
  const int b = blockIdx.x, tid = threadIdx.x;
  int zi = b * 256 + tid;
  if (zi < 4096 + 2048) tvec[zi] = 0.f;
  #pragma unroll 1
  for (int j = 0; j < 4; ++j) {
    int T = b * 4 + j;
    transpose_tile(X, XT_bf, NR, D_DIM, (T >> 4) * 32, (T & 15) * 32, tid, tile);
  }
}

// ---- kernel 2: blocks 0-255: G = X^T X split-K z=16 partials (dispatched first);
//      blocks 256-767: M-transpose; 768-895: C cvt ----
__global__ __launch_bounds__(256)
void gmc(const u16* __restrict__ XT_bf, float* __restrict__ Gpart,
         const float* __restrict__ Mm, const float* __restrict__ Cc,
         u16* __restrict__ M_bfT, u16* __restrict__ C_bf)
{
  __shared__ __align__(16) u16 As[2][8192];
  __shared__ __align__(16) u16 Bs[2][8192];
  const int b = blockIdx.x, tid = threadIdx.x;
  if (b < 256) {
    const int t = b & 15, z = b >> 4;
    const int n0 = (t & 3) * 128, m0 = (t >> 2) * 128;
    gemm_tile<0, 4>(XT_bf, XT_bf, Gpart + (size_t)z * 512 * 512, nullptr, nullptr,
                    nullptr, nullptr, nullptr, nullptr, m0, n0, 512, NR, z * 256,
                    As[0], As[1], Bs[0], Bs[1], tid);
  } else if (b < 768) {
    float* ttile = (float*)As;
    #pragma unroll 1
    for (int j = 0; j < 4; ++j) {
      int T = (b - 256) * 4 + j;   // 2048 tiles = 16 r-tiles x 128 c-tiles
      transpose_tile(Mm, M_bfT, D_DIM, MC, (T >> 7) * 32, (T & 127) * 32, tid, ttile);
    }
  } else {
    const int bb = b - 768;
    const float4* C4 = (const float4*)Cc;
    #pragma unroll 1
    for (int i = bb * 256 + tid; i < (KC * D_DIM) / 4; i += 128 * 256) {
      float4 v = C4[i];
      ushort4 r; r.x = f2bf(v.x); r.y = f2bf(v.y); r.z = f2bf(v.z); r.w = f2bf(v.w);
      *(ushort4*)&C_bf[(size_t)i * 4] = r;
    }
  }
}

// ---- kernel 3: reduce 16 partials -> G_bf. grid 256 (deterministic z-order) ----
__global__ __launch_bounds__(256)
void reduce_g(const float* __restrict__ Gpart, u16* __restrict__ G_bf)
{
  const float4* P4 = (const float4*)Gpart;
  int i = blockIdx.x * 256 + threadIdx.x;   // 65536 float4 over 65536 threads
  float4 s = {0.f, 0.f, 0.f, 0.f};
  #pragma unroll
  for (int z = 0; z < 16; ++z) {
    float4 v = P4[(size_t)z * (512 * 512 / 4) + i];
    s.x += v.x; s.y += v.y; s.z += v.z; s.w += v.w;
  }
  ushort4 r; r.x = f2bf(s.x); r.y = f2bf(s.y); r.z = f2bf(s.z); r.w = f2bf(s.w);
  *(ushort4*)&G_bf[(size_t)i * 4] = r;
}

// ---- kernel 4: mid. blocks 0-127: A^T = M^T G (+fused t); 128-191: s (+H elided) ----
__global__ __launch_bounds__(256)
void mid(const u16* __restrict__ M_bfT, const u16* __restrict__ C_bf,
         const u16* __restrict__ G_bf, const float* __restrict__ Cc,
         u16* __restrict__ A_bfT, float* __restrict__ tvec)
{
  __shared__ __align__(16) u16 As[2][8192];
  __shared__ __align__(16) u16 Bs[2][8192];
  const int b = blockIdx.x, tid = threadIdx.x;
  if (b < 128) {
    const int n0 = (b & 3) * 128, m0 = (b >> 2) * 128;
    gemm_tile<3, 8>(M_bfT, G_bf, nullptr, A_bfT, M_bfT, nullptr, tvec, nullptr, nullptr,
                    m0, n0, 512, 512, 0, As[0], As[1], Bs[0], Bs[1], tid);
  } else {
    const int u = b - 128;
    const int n0 = (u & 3) * 128, m0 = (u >> 2) * 128;
    gemm_tile<4, 8>(C_bf, G_bf, nullptr, nullptr, nullptr, Cc, tvec + 4096, nullptr,
                    nullptr, m0, n0, 512, 512, 0, As[0], As[1], Bs[0], Bs[1], tid);
  }
}

// ---- kernel 5: final. grid (32,16): out = sqrt(max(t[m] - 2*(C A^T) + s[k], 0)) ----
__global__ __launch_bounds__(256)
void final_gemm(const u16* __restrict__ C_bf, const u16* __restrict__ A_bfT,
                const float* __restrict__ tvec, float* __restrict__ out)
{
  __shared__ __align__(16) u16 As[2][8192];
  __shared__ __align__(16) u16 Bs[2][8192];
  const int n0 = blockIdx.x * 128, m0 = blockIdx.y * 128;
  gemm_tile<2, 8>(C_bf, A_bfT, out, nullptr, nullptr, nullptr, nullptr, tvec,
                  tvec + 4096, m0, n0, MC, 512, 0,
                  As[0], As[1], Bs[0], Bs[1], threadIdx.x);
}

extern "C" void kernel_launch(void* const* d_in, const int* in_sizes, int n_in,
                              void* d_out, int out_size, void* d_ws, size_t ws_size,
                              hipStream_t stream) {
  const float* X  = (const float*)d_in[0];  // [4096][512]
  const float* Mm = (const float*)d_in[1];  // [512][4096]
  const float* Cc = (const float*)d_in[2];  // [2048][512]
  float* out = (float*)d_out;               // [2048][4096]

  char* ws = (char*)d_ws;
  const size_t MB = 1u << 20;
  u16*   XT_bf = (u16*)(ws);                 // [512][4096] bf16, 4MB
  u16*   C_bf  = (u16*)(ws + 4 * MB);        // [2048][512] bf16, 2MB
  u16*   M_bfT = (u16*)(ws + 6 * MB);        // [4096][512] bf16, 4MB
  u16*   A_bfT = (u16*)(ws + 10 * MB);       // [4096][512] bf16, 4MB
  u16*   G_bf  = (u16*)(ws + 14 * MB);       // [512][512] bf16, 0.5MB
  float* tvec  = (float*)(ws + 14 * MB + 512 * 1024);  // [4096]+[2048] f32 (t then s)
  float* Gpart = (float*)(ws + 15 * MB);     // 16 x [512][512] f32, 16MB

  xprep<<<512, 256, 0, stream>>>(X, XT_bf, tvec);
  gmc<<<896, 256, 0, stream>>>(XT_bf, Gpart, Mm, Cc, M_bfT, C_bf);
  reduce_g<<<256, 256, 0, stream>>>(Gpart, G_bf);
  mid<<<192, 256, 0, stream>>>(M_bfT, C_bf, G_bf, Cc, A_bfT, tvec);
  final_gemm<<<dim3(32, 16), 256, 0, stream>>>(C_bf, A_bfT, tvec, out);
}